// Round 3
// baseline (4807.513 us; speedup 1.0000x reference)
//
#include <hip/hip_runtime.h>
#include <math.h>

#define BB 4
#define TT 2048
#define DD 1024
#define HH 128
#define EPSF 1e-6f
#define BT (BB*TT)   // 8192
#define CH 64        // pass1 chunk
#define NCH (TT/CH)  // 32
#define CP 128       // pass2 chunk
#define NCP (TT/CP)  // 16

// ---------------------------------------------------------------------------
// Projection: P[bt][h] = sum_d x[bt][d] * W[h][d] + bias[h]
// ---------------------------------------------------------------------------
__global__ __launch_bounds__(256) void proj_kernel(
    const float* __restrict__ x,
    const float* __restrict__ Wq, const float* __restrict__ bq,
    const float* __restrict__ Wk, const float* __restrict__ bk,
    const float* __restrict__ Wv, const float* __restrict__ bv,
    float* __restrict__ Q, float* __restrict__ K, float* __restrict__ V)
{
    const int which = blockIdx.y;
    const float* W    = (which == 0) ? Wq : (which == 1) ? Wk : Wv;
    const float* bias = (which == 0) ? bq : (which == 1) ? bk : bv;
    float* P          = (which == 0) ? Q  : (which == 1) ? K  : V;

    const int row0 = blockIdx.x * 64;

    __shared__ float xT[32][68];
    __shared__ float wT[32][132];

    const int tid = threadIdx.x;
    const int tx = tid & 15;
    const int ty = tid >> 4;

    float acc[4][8];
    #pragma unroll
    for (int i = 0; i < 4; i++)
        #pragma unroll
        for (int j = 0; j < 8; j++) acc[i][j] = 0.f;

    for (int k0 = 0; k0 < DD; k0 += 32) {
        #pragma unroll
        for (int l = 0; l < 2; l++) {
            int f = tid + l * 256;
            int r = f >> 3;
            int cg = f & 7;
            float4 v = *(const float4*)(x + (size_t)(row0 + r) * DD + k0 + cg * 4);
            xT[cg*4+0][r] = v.x; xT[cg*4+1][r] = v.y;
            xT[cg*4+2][r] = v.z; xT[cg*4+3][r] = v.w;
        }
        #pragma unroll
        for (int l = 0; l < 4; l++) {
            int f = tid + l * 256;
            int h = f >> 3;
            int cg = f & 7;
            float4 v = *(const float4*)(W + (size_t)h * DD + k0 + cg * 4);
            wT[cg*4+0][h] = v.x; wT[cg*4+1][h] = v.y;
            wT[cg*4+2][h] = v.z; wT[cg*4+3][h] = v.w;
        }
        __syncthreads();
        #pragma unroll
        for (int kk = 0; kk < 32; kk++) {
            float4 xv = *(const float4*)&xT[kk][ty * 4];
            float4 w0 = *(const float4*)&wT[kk][tx * 8];
            float4 w1 = *(const float4*)&wT[kk][tx * 8 + 4];
            float xa[4] = {xv.x, xv.y, xv.z, xv.w};
            float wa[8] = {w0.x, w0.y, w0.z, w0.w, w1.x, w1.y, w1.z, w1.w};
            #pragma unroll
            for (int i = 0; i < 4; i++)
                #pragma unroll
                for (int j = 0; j < 8; j++)
                    acc[i][j] += xa[i] * wa[j];
        }
        __syncthreads();
    }

    #pragma unroll
    for (int i = 0; i < 4; i++) {
        int row = row0 + ty * 4 + i;
        #pragma unroll
        for (int j = 0; j < 8; j++) acc[i][j] += bias[tx * 8 + j];
        float4 o0 = {acc[i][0], acc[i][1], acc[i][2], acc[i][3]};
        float4 o1 = {acc[i][4], acc[i][5], acc[i][6], acc[i][7]};
        *(float4*)(P + (size_t)row * HH + tx * 8)     = o0;
        *(float4*)(P + (size_t)row * HH + tx * 8 + 4) = o1;
    }
}

// ---------------------------------------------------------------------------
// Pass 1: sequential-over-chunks Woodbury. grid = BB, block = 256.
// Per chunk (C=64):  W = U*A0 ; F = I + W*U^T ; LDL^T elim -> R'=L^-1 W in W;
// alpha_i = (s_i/d_i) R'[i,:] ; A0 -= Rhat^T Rhat with Rhat = D^-1/2 R'.
// LDS: A0[128][132] U[64][132] W[64][132] F[64][68] ss[64] ls[64] = 149.5 KB
// ---------------------------------------------------------------------------
__global__ __launch_bounds__(256) void pass1_kernel(
    const float* __restrict__ Q, const float* __restrict__ K,
    float* __restrict__ alpha)
{
    extern __shared__ float lds[];
    float* A0 = lds;                  // 128*132
    float* Us = A0 + 128*132;         // 64*132
    float* Ws = Us + 64*132;          // 64*132
    float* Fs = Ws + 64*132;          // 64*68
    float* ss = Fs + 64*68;           // 64
    float* ls = ss + 64;              // 64

    const int b = blockIdx.x;
    const int tid = threadIdx.x;
    const float* Qb = Q + (size_t)b * TT * HH;
    const float* Kb = K + (size_t)b * TT * HH;
    float* ab = alpha + (size_t)b * TT * HH;

    // A0 = I (lambda0 = 1)
    for (int idx = tid; idx < 128*132; idx += 256) A0[idx] = 0.f;
    __syncthreads();
    for (int r = tid; r < 128; r += 256) A0[r*132 + r] = 1.0f;
    __syncthreads();

    const int tx = tid & 15;
    const int ty = tid >> 4;

    for (int ch = 0; ch < NCH; ch++) {
        const int t0 = ch * CH;

        // ---- P0: build u rows (unit k) and s_i = k.q
        {
            const int i = tid >> 2, p = tid & 3, cp = p * 32;
            const float* krow = Kb + (size_t)(t0 + i) * HH + cp;
            const float* qrow = Qb + (size_t)(t0 + i) * HH + cp;
            float4 kv[8];
            float kk = 0.f, kq = 0.f;
            #pragma unroll
            for (int j = 0; j < 8; j++) {
                kv[j] = *(const float4*)(krow + 4*j);
                float4 qv = *(const float4*)(qrow + 4*j);
                kk += kv[j].x*kv[j].x + kv[j].y*kv[j].y + kv[j].z*kv[j].z + kv[j].w*kv[j].w;
                kq += kv[j].x*qv.x + kv[j].y*qv.y + kv[j].z*qv.z + kv[j].w*qv.w;
            }
            kk += __shfl_xor(kk, 1); kk += __shfl_xor(kk, 2);
            kq += __shfl_xor(kq, 1); kq += __shfl_xor(kq, 2);
            float rn = 1.0f / (sqrtf(kk) + EPSF);
            #pragma unroll
            for (int j = 0; j < 8; j++) {
                float4 u = {kv[j].x*rn, kv[j].y*rn, kv[j].z*rn, kv[j].w*rn};
                *(float4*)&Us[i*132 + cp + 4*j] = u;
            }
            if (p == 0) ss[i] = kq;
        }
        __syncthreads();

        // ---- P1: W = U * A0   (rows i = ty+16r, cols c0 = tx*8)
        {
            const int c0 = tx * 8;
            float acc[4][8];
            #pragma unroll
            for (int r = 0; r < 4; r++)
                #pragma unroll
                for (int j = 0; j < 8; j++) acc[r][j] = 0.f;
            for (int k0 = 0; k0 < HH; k0 += 4) {
                float4 uu[4];
                #pragma unroll
                for (int r = 0; r < 4; r++)
                    uu[r] = *(const float4*)&Us[(ty + 16*r)*132 + k0];
                #pragma unroll
                for (int kk = 0; kk < 4; kk++) {
                    float4 a0 = *(const float4*)&A0[(k0+kk)*132 + c0];
                    float4 a1 = *(const float4*)&A0[(k0+kk)*132 + c0 + 4];
                    float av[8] = {a0.x,a0.y,a0.z,a0.w,a1.x,a1.y,a1.z,a1.w};
                    #pragma unroll
                    for (int r = 0; r < 4; r++) {
                        float u = (kk==0)?uu[r].x:(kk==1)?uu[r].y:(kk==2)?uu[r].z:uu[r].w;
                        #pragma unroll
                        for (int jx = 0; jx < 8; jx++) acc[r][jx] += u * av[jx];
                    }
                }
            }
            #pragma unroll
            for (int r = 0; r < 4; r++) {
                int row = ty + 16*r;
                *(float4*)&Ws[row*132 + c0]     = make_float4(acc[r][0],acc[r][1],acc[r][2],acc[r][3]);
                *(float4*)&Ws[row*132 + c0 + 4] = make_float4(acc[r][4],acc[r][5],acc[r][6],acc[r][7]);
            }
        }
        __syncthreads();

        // ---- P2: F = I + W * U^T  (i = ty+16r, j = tx+16s)
        {
            float acc2[4][4];
            #pragma unroll
            for (int r = 0; r < 4; r++)
                #pragma unroll
                for (int s = 0; s < 4; s++) acc2[r][s] = 0.f;
            for (int k0 = 0; k0 < HH; k0 += 4) {
                float4 wv[4], uv[4];
                #pragma unroll
                for (int r = 0; r < 4; r++) wv[r] = *(const float4*)&Ws[(ty+16*r)*132 + k0];
                #pragma unroll
                for (int s = 0; s < 4; s++) uv[s] = *(const float4*)&Us[(tx+16*s)*132 + k0];
                #pragma unroll
                for (int r = 0; r < 4; r++)
                    #pragma unroll
                    for (int s = 0; s < 4; s++)
                        acc2[r][s] += wv[r].x*uv[s].x + wv[r].y*uv[s].y
                                    + wv[r].z*uv[s].z + wv[r].w*uv[s].w;
            }
            #pragma unroll
            for (int r = 0; r < 4; r++)
                #pragma unroll
                for (int s = 0; s < 4; s++) {
                    int i = ty + 16*r, j = tx + 16*s;
                    Fs[i*68 + j] = acc2[r][s] + ((i == j) ? 1.0f : 0.0f);
                }
        }
        __syncthreads();

        // ---- P3: LDL^T forward elimination on [F | W]
        for (int j = 0; j < CH; j++) {
            float dinv = 1.0f / Fs[j*68 + j];   // row j final after prev step
            if (tid > j && tid < CH) ls[tid] = Fs[tid*68 + j] * dinv;
            __syncthreads();
            const int cg = tid & 7;
            const int ri = tid >> 3;
            const int cbase = cg * 24;
            #pragma unroll
            for (int pass = 0; pass < 2; pass++) {
                int i = j + 1 + ri + pass*32;
                if (i < CH) {
                    float l = ls[i];
                    #pragma unroll
                    for (int cc = 0; cc < 24; cc += 4) {
                        int c = cbase + cc;
                        if (c < 64) {
                            float4 rj = *(const float4*)&Fs[j*68 + c];
                            float4 rv = *(float4*)&Fs[i*68 + c];
                            rv.x -= l*rj.x; rv.y -= l*rj.y; rv.z -= l*rj.z; rv.w -= l*rj.w;
                            *(float4*)&Fs[i*68 + c] = rv;
                        } else {
                            float4 rj = *(const float4*)&Ws[j*132 + (c-64)];
                            float4 rv = *(float4*)&Ws[i*132 + (c-64)];
                            rv.x -= l*rj.x; rv.y -= l*rj.y; rv.z -= l*rj.z; rv.w -= l*rj.w;
                            *(float4*)&Ws[i*132 + (c-64)] = rv;
                        }
                    }
                }
            }
            __syncthreads();
        }

        // ---- P5': alpha out + scale rows by sqrt(dinv)
        {
            const int i = tid >> 2, p = tid & 3, cp = p * 32;
            float d = Fs[i*68 + i];
            float dinv = 1.0f / d;
            float ca = ss[i] * dinv;
            float cs = sqrtf(dinv);
            float* wrow = &Ws[i*132 + cp];
            float* arow = ab + (size_t)(t0 + i) * HH + cp;
            #pragma unroll
            for (int jj = 0; jj < 32; jj += 4) {
                float4 w = *(const float4*)&wrow[jj];
                *(float4*)&arow[jj] = make_float4(ca*w.x, ca*w.y, ca*w.z, ca*w.w);
                *(float4*)&wrow[jj] = make_float4(cs*w.x, cs*w.y, cs*w.z, cs*w.w);
            }
        }
        __syncthreads();

        // ---- P6: A0 -= Rhat^T Rhat   (skip last chunk)
        if (ch != NCH - 1) {
            const int r0 = (tid >> 4) * 8, c0 = (tid & 15) * 8;
            float acc[8][8];
            #pragma unroll
            for (int a = 0; a < 8; a++)
                #pragma unroll
                for (int bb = 0; bb < 8; bb++) acc[a][bb] = 0.f;
            for (int i = 0; i < CH; i++) {
                float4 ra = *(const float4*)&Ws[i*132 + r0];
                float4 rb = *(const float4*)&Ws[i*132 + r0 + 4];
                float4 ca_ = *(const float4*)&Ws[i*132 + c0];
                float4 cb = *(const float4*)&Ws[i*132 + c0 + 4];
                float rr[8] = {ra.x,ra.y,ra.z,ra.w,rb.x,rb.y,rb.z,rb.w};
                float cc[8] = {ca_.x,ca_.y,ca_.z,ca_.w,cb.x,cb.y,cb.z,cb.w};
                #pragma unroll
                for (int a = 0; a < 8; a++)
                    #pragma unroll
                    for (int bb = 0; bb < 8; bb++) acc[a][bb] += rr[a]*cc[bb];
            }
            #pragma unroll
            for (int a = 0; a < 8; a++) {
                #pragma unroll
                for (int b4 = 0; b4 < 8; b4 += 4) {
                    float4 v = *(float4*)&A0[(r0+a)*132 + c0 + b4];
                    v.x -= acc[a][b4+0]; v.y -= acc[a][b4+1];
                    v.z -= acc[a][b4+2]; v.w -= acc[a][b4+3];
                    *(float4*)&A0[(r0+a)*132 + c0 + b4] = v;
                }
            }
        }
        __syncthreads();
    }
}

// ---------------------------------------------------------------------------
// Chunk sums: St_c[x][h] = sum_{t in chunk} alpha[t,x] * v[t,h]  (= M^T block)
// grid = BB*NCP, block = 256.
// ---------------------------------------------------------------------------
__global__ __launch_bounds__(256) void chunk_sum_kernel(
    const float* __restrict__ alpha, const float* __restrict__ V,
    float* __restrict__ S)
{
    const int bidx = blockIdx.x;
    const int b = bidx >> 4, c = bidx & 15;
    const int tid = threadIdx.x;
    const int x0 = (tid >> 4) * 8, h0 = (tid & 15) * 8;
    const float* arow = alpha + ((size_t)b * TT + c * CP) * HH;
    const float* vrow = V + ((size_t)b * TT + c * CP) * HH;
    float acc[8][8];
    #pragma unroll
    for (int a = 0; a < 8; a++)
        #pragma unroll
        for (int h = 0; h < 8; h++) acc[a][h] = 0.f;
    for (int t = 0; t < CP; t++) {
        float4 a0 = *(const float4*)&arow[(size_t)t*HH + x0];
        float4 a1 = *(const float4*)&arow[(size_t)t*HH + x0 + 4];
        float4 v0 = *(const float4*)&vrow[(size_t)t*HH + h0];
        float4 v1 = *(const float4*)&vrow[(size_t)t*HH + h0 + 4];
        float aa[8] = {a0.x,a0.y,a0.z,a0.w,a1.x,a1.y,a1.z,a1.w};
        float vv[8] = {v0.x,v0.y,v0.z,v0.w,v1.x,v1.y,v1.z,v1.w};
        #pragma unroll
        for (int a = 0; a < 8; a++)
            #pragma unroll
            for (int h = 0; h < 8; h++) acc[a][h] += aa[a]*vv[h];
    }
    float* Sblk = S + (size_t)(b * NCP + c) * HH * HH;
    #pragma unroll
    for (int a = 0; a < 8; a++) {
        #pragma unroll
        for (int h4 = 0; h4 < 8; h4 += 4)
            *(float4*)&Sblk[(size_t)(x0+a)*HH + h0 + h4] =
                make_float4(acc[a][h4],acc[a][h4+1],acc[a][h4+2],acc[a][h4+3]);
    }
}

// ---------------------------------------------------------------------------
// Chunk output: O_c = tril(Qc alpha_c^T) Vc + Qc M_c^T, M_c^T = sum_{c'<c} St
// grid = BB*NCP, block = 256. LDS: Mt[128][132] + Pt[128][132] = 132 KB.
// ---------------------------------------------------------------------------
__global__ __launch_bounds__(256) void chunk_out_kernel(
    const float* __restrict__ Qm, const float* __restrict__ alpha,
    const float* __restrict__ V, const float* __restrict__ S,
    float* __restrict__ O)
{
    extern __shared__ float lds[];
    float* Mt = lds;            // 128*132
    float* Pt = Mt + 128*132;   // 128*132

    const int bidx = blockIdx.x;
    const int b = bidx >> 4, c = bidx & 15;
    const int tid = threadIdx.x;
    const float* qrow = Qm + ((size_t)b * TT + c * CP) * HH;
    const float* arow = alpha + ((size_t)b * TT + c * CP) * HH;
    const float* vrow = V + ((size_t)b * TT + c * CP) * HH;

    // phase A: Mt = sum_{c'<c} St
    for (int idx4 = tid; idx4 < (HH*HH)/4; idx4 += 256) {
        int x = idx4 >> 5;
        int h4 = (idx4 & 31) * 4;
        float4 s = make_float4(0.f,0.f,0.f,0.f);
        for (int cp = 0; cp < c; cp++) {
            float4 v = *(const float4*)&S[(size_t)(b*NCP+cp)*HH*HH + (size_t)x*HH + h4];
            s.x += v.x; s.y += v.y; s.z += v.z; s.w += v.w;
        }
        *(float4*)&Mt[x*132 + h4] = s;
    }

    // phase B: Pt[s][t] = (s<=t) ? q_t . alpha_s : 0
    {
        const int s0 = (tid >> 4) * 8, t0l = (tid & 15) * 8;
        float accB[8][8];
        #pragma unroll
        for (int a = 0; a < 8; a++)
            #pragma unroll
            for (int t = 0; t < 8; t++) accB[a][t] = 0.f;
        for (int k0 = 0; k0 < HH; k0 += 4) {
            float4 qv[8], av[8];
            #pragma unroll
            for (int t = 0; t < 8; t++) qv[t] = *(const float4*)&qrow[(size_t)(t0l+t)*HH + k0];
            #pragma unroll
            for (int a = 0; a < 8; a++) av[a] = *(const float4*)&arow[(size_t)(s0+a)*HH + k0];
            #pragma unroll
            for (int a = 0; a < 8; a++)
                #pragma unroll
                for (int t = 0; t < 8; t++)
                    accB[a][t] += av[a].x*qv[t].x + av[a].y*qv[t].y
                                + av[a].z*qv[t].z + av[a].w*qv[t].w;
        }
        __syncthreads();   // phase A complete before C reads Mt; also before Pt stores read
        #pragma unroll
        for (int a = 0; a < 8; a++)
            #pragma unroll
            for (int t = 0; t < 8; t++) {
                int sg = s0 + a, tg = t0l + t;
                Pt[sg*132 + tg] = (sg <= tg) ? accB[a][t] : 0.f;
            }
    }
    __syncthreads();

    // phase C: O[t,h] = sum_s Pt[s][t] V[s,h] + sum_x q[t,x] Mt[x][h]
    {
        const int tr0 = (tid >> 4) * 8, h0 = (tid & 15) * 8;
        float acc[8][8];
        #pragma unroll
        for (int a = 0; a < 8; a++)
            #pragma unroll
            for (int h = 0; h < 8; h++) acc[a][h] = 0.f;
        for (int s = 0; s < CP; s++) {
            float4 p0 = *(const float4*)&Pt[s*132 + tr0];
            float4 p1 = *(const float4*)&Pt[s*132 + tr0 + 4];
            float4 v0 = *(const float4*)&vrow[(size_t)s*HH + h0];
            float4 v1 = *(const float4*)&vrow[(size_t)s*HH + h0 + 4];
            float pp[8] = {p0.x,p0.y,p0.z,p0.w,p1.x,p1.y,p1.z,p1.w};
            float vv[8] = {v0.x,v0.y,v0.z,v0.w,v1.x,v1.y,v1.z,v1.w};
            #pragma unroll
            for (int a = 0; a < 8; a++)
                #pragma unroll
                for (int h = 0; h < 8; h++) acc[a][h] += pp[a]*vv[h];
        }
        for (int x0 = 0; x0 < HH; x0 += 4) {
            float4 qv[8];
            #pragma unroll
            for (int a = 0; a < 8; a++) qv[a] = *(const float4*)&qrow[(size_t)(tr0+a)*HH + x0];
            #pragma unroll
            for (int kk = 0; kk < 4; kk++) {
                float4 m0 = *(const float4*)&Mt[(x0+kk)*132 + h0];
                float4 m1 = *(const float4*)&Mt[(x0+kk)*132 + h0 + 4];
                float mm[8] = {m0.x,m0.y,m0.z,m0.w,m1.x,m1.y,m1.z,m1.w};
                #pragma unroll
                for (int a = 0; a < 8; a++) {
                    float qq = (kk==0)?qv[a].x:(kk==1)?qv[a].y:(kk==2)?qv[a].z:qv[a].w;
                    #pragma unroll
                    for (int h = 0; h < 8; h++) acc[a][h] += qq*mm[h];
                }
            }
        }
        float* orow = O + ((size_t)b * TT + c * CP) * HH;
        #pragma unroll
        for (int a = 0; a < 8; a++) {
            #pragma unroll
            for (int h4 = 0; h4 < 8; h4 += 4)
                *(float4*)&orow[(size_t)(tr0+a)*HH + h0 + h4] =
                    make_float4(acc[a][h4],acc[a][h4+1],acc[a][h4+2],acc[a][h4+3]);
        }
    }
}

// ---------------------------------------------------------------------------
// Output: out[bt][d] = sum_h O[bt][h] * Wo[d][h] + bo[d]
// ---------------------------------------------------------------------------
__global__ __launch_bounds__(256) void out_kernel(
    const float* __restrict__ O, const float* __restrict__ Wo,
    const float* __restrict__ bo, float* __restrict__ out)
{
    const int row0 = blockIdx.x * 64;
    const int d0   = blockIdx.y * 128;

    __shared__ float oT[32][68];
    __shared__ float woT[32][132];

    const int tid = threadIdx.x;
    const int tx = tid & 15;
    const int ty = tid >> 4;

    float acc[4][8];
    #pragma unroll
    for (int i = 0; i < 4; i++)
        #pragma unroll
        for (int j = 0; j < 8; j++) acc[i][j] = 0.f;

    for (int k0 = 0; k0 < HH; k0 += 32) {
        #pragma unroll
        for (int l = 0; l < 2; l++) {
            int f = tid + l * 256;
            int r = f >> 3;
            int cg = f & 7;
            float4 v = *(const float4*)(O + (size_t)(row0 + r) * HH + k0 + cg * 4);
            oT[cg*4+0][r] = v.x; oT[cg*4+1][r] = v.y;
            oT[cg*4+2][r] = v.z; oT[cg*4+3][r] = v.w;
        }
        #pragma unroll
        for (int l = 0; l < 4; l++) {
            int f = tid + l * 256;
            int d = f >> 3;
            int cg = f & 7;
            float4 v = *(const float4*)(Wo + (size_t)(d0 + d) * HH + k0 + cg * 4);
            woT[cg*4+0][d] = v.x; woT[cg*4+1][d] = v.y;
            woT[cg*4+2][d] = v.z; woT[cg*4+3][d] = v.w;
        }
        __syncthreads();
        #pragma unroll
        for (int kk = 0; kk < 32; kk++) {
            float4 ov = *(const float4*)&oT[kk][ty * 4];
            float4 w0 = *(const float4*)&woT[kk][tx * 8];
            float4 w1 = *(const float4*)&woT[kk][tx * 8 + 4];
            float oa[4] = {ov.x, ov.y, ov.z, ov.w};
            float wa[8] = {w0.x, w0.y, w0.z, w0.w, w1.x, w1.y, w1.z, w1.w};
            #pragma unroll
            for (int i = 0; i < 4; i++)
                #pragma unroll
                for (int j = 0; j < 8; j++)
                    acc[i][j] += oa[i] * wa[j];
        }
        __syncthreads();
    }

    #pragma unroll
    for (int i = 0; i < 4; i++) {
        int row = row0 + ty * 4 + i;
        #pragma unroll
        for (int j = 0; j < 8; j++) acc[i][j] += bo[d0 + tx * 8 + j];
        float4 o0 = {acc[i][0], acc[i][1], acc[i][2], acc[i][3]};
        float4 o1 = {acc[i][4], acc[i][5], acc[i][6], acc[i][7]};
        *(float4*)(out + (size_t)row * DD + d0 + tx * 8)     = o0;
        *(float4*)(out + (size_t)row * DD + d0 + tx * 8 + 4) = o1;
    }
}

extern "C" void kernel_launch(void* const* d_in, const int* in_sizes, int n_in,
                              void* d_out, int out_size, void* d_ws, size_t ws_size,
                              hipStream_t stream) {
    const float* x  = (const float*)d_in[0];
    const float* Wq = (const float*)d_in[1];
    const float* bq = (const float*)d_in[2];
    const float* Wk = (const float*)d_in[3];
    const float* bk = (const float*)d_in[4];
    const float* Wv = (const float*)d_in[5];
    const float* bv = (const float*)d_in[6];
    const float* Wo = (const float*)d_in[7];
    const float* bo = (const float*)d_in[8];
    float* out = (float*)d_out;

    float* ws = (float*)d_ws;
    float* Q = ws;                          // BT*HH
    float* K = ws + (size_t)BT * HH;        // BT*HH   (reused as O)
    float* V = ws + (size_t)2 * BT * HH;    // BT*HH
    float* S = ws + (size_t)3 * BT * HH;    // BB*NCP*HH*HH = BT*HH floats
    float* O = K;                           // K dead after pass1
    float* alpha = out;                     // staged in d_out (dead before out_kernel)

    dim3 pgrid(BT / 64, 3);
    proj_kernel<<<pgrid, 256, 0, stream>>>(x, Wq, bq, Wk, bk, Wv, bv, Q, K, V);

    const size_t p1_lds = (size_t)(128*132 + 64*132 + 64*132 + 64*68 + 64 + 64) * 4;
    pass1_kernel<<<BB, 256, p1_lds, stream>>>(Q, K, alpha);

    chunk_sum_kernel<<<BB * NCP, 256, 0, stream>>>(alpha, V, S);

    const size_t k4_lds = (size_t)(2 * 128 * 132) * 4;
    chunk_out_kernel<<<BB * NCP, 256, k4_lds, stream>>>(Q, alpha, V, S, O);

    dim3 ogrid(BT / 64, DD / 128);
    out_kernel<<<ogrid, 256, 0, stream>>>(O, Wo, bo, out);
}

// Round 4
// 3504.183 us; speedup vs baseline: 1.3719x; 1.3719x over previous
//
#include <hip/hip_runtime.h>
#include <math.h>

#define BB 4
#define TT 2048
#define DD 1024
#define HH 128
#define EPSF 1e-6f
#define BT (BB*TT)   // 8192
#define CH 64        // pass1 chunk
#define NCH (TT/CH)  // 32
#define CP 128       // pass2 chunk
#define NCP (TT/CP)  // 16

// ---------------------------------------------------------------------------
// Projection: P[bt][h] = sum_d x[bt][d] * W[h][d] + bias[h]
// ---------------------------------------------------------------------------
__global__ __launch_bounds__(256) void proj_kernel(
    const float* __restrict__ x,
    const float* __restrict__ Wq, const float* __restrict__ bq,
    const float* __restrict__ Wk, const float* __restrict__ bk,
    const float* __restrict__ Wv, const float* __restrict__ bv,
    float* __restrict__ Q, float* __restrict__ K, float* __restrict__ V)
{
    const int which = blockIdx.y;
    const float* W    = (which == 0) ? Wq : (which == 1) ? Wk : Wv;
    const float* bias = (which == 0) ? bq : (which == 1) ? bk : bv;
    float* P          = (which == 0) ? Q  : (which == 1) ? K  : V;

    const int row0 = blockIdx.x * 64;

    __shared__ float xT[32][68];
    __shared__ float wT[32][132];

    const int tid = threadIdx.x;
    const int tx = tid & 15;
    const int ty = tid >> 4;

    float acc[4][8];
    #pragma unroll
    for (int i = 0; i < 4; i++)
        #pragma unroll
        for (int j = 0; j < 8; j++) acc[i][j] = 0.f;

    for (int k0 = 0; k0 < DD; k0 += 32) {
        #pragma unroll
        for (int l = 0; l < 2; l++) {
            int f = tid + l * 256;
            int r = f >> 3;
            int cg = f & 7;
            float4 v = *(const float4*)(x + (size_t)(row0 + r) * DD + k0 + cg * 4);
            xT[cg*4+0][r] = v.x; xT[cg*4+1][r] = v.y;
            xT[cg*4+2][r] = v.z; xT[cg*4+3][r] = v.w;
        }
        #pragma unroll
        for (int l = 0; l < 4; l++) {
            int f = tid + l * 256;
            int h = f >> 3;
            int cg = f & 7;
            float4 v = *(const float4*)(W + (size_t)h * DD + k0 + cg * 4);
            wT[cg*4+0][h] = v.x; wT[cg*4+1][h] = v.y;
            wT[cg*4+2][h] = v.z; wT[cg*4+3][h] = v.w;
        }
        __syncthreads();
        #pragma unroll
        for (int kk = 0; kk < 32; kk++) {
            float4 xv = *(const float4*)&xT[kk][ty * 4];
            float4 w0 = *(const float4*)&wT[kk][tx * 8];
            float4 w1 = *(const float4*)&wT[kk][tx * 8 + 4];
            float xa[4] = {xv.x, xv.y, xv.z, xv.w};
            float wa[8] = {w0.x, w0.y, w0.z, w0.w, w1.x, w1.y, w1.z, w1.w};
            #pragma unroll
            for (int i = 0; i < 4; i++)
                #pragma unroll
                for (int j = 0; j < 8; j++)
                    acc[i][j] += xa[i] * wa[j];
        }
        __syncthreads();
    }

    #pragma unroll
    for (int i = 0; i < 4; i++) {
        int row = row0 + ty * 4 + i;
        #pragma unroll
        for (int j = 0; j < 8; j++) acc[i][j] += bias[tx * 8 + j];
        float4 o0 = {acc[i][0], acc[i][1], acc[i][2], acc[i][3]};
        float4 o1 = {acc[i][4], acc[i][5], acc[i][6], acc[i][7]};
        *(float4*)(P + (size_t)row * HH + tx * 8)     = o0;
        *(float4*)(P + (size_t)row * HH + tx * 8 + 4) = o1;
    }
}

// ---------------------------------------------------------------------------
// Pass 1 (rewritten): chunked Woodbury, serial core = ONE WAVE, in-register,
// fully unrolled, zero barriers inside. grid = BB, block = 512.
// Per chunk: U,s (P0) ; W = U*A0 (P1) ; F = I + W*U^T (P2) ;
// wave0: LDL of F + X = L^-1 via shuffles (f,g in regs) -> X,dinv to LDS ;
// G = X*W, alpha = s*dinv*G, Ghat = sqrt(dinv)*G (P4) ; A0 -= Ghat^T Ghat (P6).
// LDS floats: A0 128*132 | Us/G 64*132 | Ws 64*132 | Fs/X 64*68 | ss 64 | dinv 64
// ---------------------------------------------------------------------------
__global__ __launch_bounds__(512) void pass1_kernel(
    const float* __restrict__ Q, const float* __restrict__ K,
    float* __restrict__ alpha)
{
    extern __shared__ float lds[];
    float* A0    = lds;            // 128*132
    float* Us    = A0 + 128*132;   // 64*132  (becomes Ghat after P4)
    float* Ws    = Us + 64*132;    // 64*132
    float* Fs    = Ws + 64*132;    // 64*68   (becomes X after serial core)
    float* ss    = Fs + 64*68;     // 64
    float* dinvs = ss + 64;        // 64

    const int b   = blockIdx.x;
    const int tid = threadIdx.x;
    const float* Qb = Q + (size_t)b * TT * HH;
    const float* Kb = K + (size_t)b * TT * HH;
    float* ab = alpha + (size_t)b * TT * HH;

    // A0 = I  (lambda0 = 1)
    for (int idx = tid; idx < 128*132; idx += 512) A0[idx] = 0.f;
    __syncthreads();
    if (tid < 128) A0[tid*132 + tid] = 1.0f;
    __syncthreads();

    const int ty = tid >> 4;      // 0..31
    const int tx = tid & 15;      // 0..15
    const int i8 = tid >> 3;      // 0..63
    const int p8 = tid & 7;       // 0..7

    for (int ch = 0; ch < NCH; ch++) {
        const int t0 = ch * CH;

        // ---- P0: U rows (unit k) + ss
        {
            const float* krow = Kb + (size_t)(t0 + i8) * HH + p8 * 16;
            const float* qrow = Qb + (size_t)(t0 + i8) * HH + p8 * 16;
            float4 kv[4];
            float kk = 0.f, kq = 0.f;
            #pragma unroll
            for (int j = 0; j < 4; j++) {
                kv[j] = *(const float4*)(krow + 4*j);
                float4 qv = *(const float4*)(qrow + 4*j);
                kk += kv[j].x*kv[j].x + kv[j].y*kv[j].y + kv[j].z*kv[j].z + kv[j].w*kv[j].w;
                kq += kv[j].x*qv.x + kv[j].y*qv.y + kv[j].z*qv.z + kv[j].w*qv.w;
            }
            kk += __shfl_xor(kk, 1); kk += __shfl_xor(kk, 2); kk += __shfl_xor(kk, 4);
            kq += __shfl_xor(kq, 1); kq += __shfl_xor(kq, 2); kq += __shfl_xor(kq, 4);
            float rn = 1.0f / (sqrtf(kk) + EPSF);
            #pragma unroll
            for (int j = 0; j < 4; j++)
                *(float4*)&Us[i8*132 + p8*16 + 4*j] =
                    make_float4(kv[j].x*rn, kv[j].y*rn, kv[j].z*rn, kv[j].w*rn);
            if (p8 == 0) ss[i8] = kq;
        }
        __syncthreads();   // B1

        // ---- P1: W = U * A0   (rows {ty, ty+32}, cols tx*8..+7)
        {
            float acc[2][8];
            #pragma unroll
            for (int r = 0; r < 2; r++)
                #pragma unroll
                for (int j = 0; j < 8; j++) acc[r][j] = 0.f;
            for (int k = 0; k < HH; k += 4) {
                float4 u0 = *(const float4*)&Us[ty*132 + k];
                float4 u1 = *(const float4*)&Us[(ty+32)*132 + k];
                #pragma unroll
                for (int kk2 = 0; kk2 < 4; kk2++) {
                    float4 a0 = *(const float4*)&A0[(k+kk2)*132 + tx*8];
                    float4 a1 = *(const float4*)&A0[(k+kk2)*132 + tx*8 + 4];
                    float av[8] = {a0.x,a0.y,a0.z,a0.w,a1.x,a1.y,a1.z,a1.w};
                    float e0 = (kk2==0)?u0.x:(kk2==1)?u0.y:(kk2==2)?u0.z:u0.w;
                    float e1 = (kk2==0)?u1.x:(kk2==1)?u1.y:(kk2==2)?u1.z:u1.w;
                    #pragma unroll
                    for (int jx = 0; jx < 8; jx++) {
                        acc[0][jx] += e0 * av[jx];
                        acc[1][jx] += e1 * av[jx];
                    }
                }
            }
            *(float4*)&Ws[ty*132 + tx*8]          = make_float4(acc[0][0],acc[0][1],acc[0][2],acc[0][3]);
            *(float4*)&Ws[ty*132 + tx*8 + 4]      = make_float4(acc[0][4],acc[0][5],acc[0][6],acc[0][7]);
            *(float4*)&Ws[(ty+32)*132 + tx*8]     = make_float4(acc[1][0],acc[1][1],acc[1][2],acc[1][3]);
            *(float4*)&Ws[(ty+32)*132 + tx*8 + 4] = make_float4(acc[1][4],acc[1][5],acc[1][6],acc[1][7]);
        }
        __syncthreads();   // B2

        // ---- P2: F = I + W * U^T   (row i8, cols p8*8..+7)
        {
            float acc[8];
            #pragma unroll
            for (int jj = 0; jj < 8; jj++) acc[jj] = 0.f;
            for (int k = 0; k < HH; k += 4) {
                float4 w = *(const float4*)&Ws[i8*132 + k];
                #pragma unroll
                for (int jj = 0; jj < 8; jj++) {
                    float4 u = *(const float4*)&Us[(p8*8+jj)*132 + k];
                    acc[jj] += w.x*u.x + w.y*u.y + w.z*u.z + w.w*u.w;
                }
            }
            #pragma unroll
            for (int jj = 0; jj < 8; jj++) {
                int j = p8*8 + jj;
                Fs[i8*68 + j] = acc[jj] + ((i8 == j) ? 1.0f : 0.0f);
            }
        }
        __syncthreads();   // B3

        // ---- Serial core (wave 0 only): LDL of F + X = L^-1, registers+shuffles.
        // Lane c owns column c of F (symmetric) and of X. Fully unrolled.
        if (tid < 64) {
            const int c = tid;
            float f[64], g[64];
            #pragma unroll
            for (int i = 0; i < 64; i++) f[i] = Fs[i*68 + c];
            #pragma unroll
            for (int i = 0; i < 64; i++) g[i] = (i == c) ? 1.0f : 0.0f;
            #pragma unroll
            for (int j = 0; j < 64; j++) {
                float dj = __shfl(f[j], j);          // pivot F[j][j]
                float dinv = 1.0f / dj;
                dinvs[j] = dinv;                     // same addr/val all lanes
                float tt = f[j] * dinv;              // F[j][c]/d_j
                float mm = g[j] * dinv;              // X[j][c]/d_j
                #pragma unroll
                for (int i = j + 1; i < 64; i++) {
                    float sij = __shfl(f[i], j);     // F[i][j]
                    f[i] -= sij * tt;
                    g[i] -= sij * mm;
                }
            }
            #pragma unroll
            for (int i = 0; i < 64; i++) Fs[i*68 + c] = g[i];   // X row-major
        }
        __syncthreads();   // B4

        // ---- P4: G = X * W ; alpha = (s*dinv)*G -> global ; Ghat = sqrt(dinv)*G -> Us
        {
            float acc[2][8];
            #pragma unroll
            for (int r = 0; r < 2; r++)
                #pragma unroll
                for (int j = 0; j < 8; j++) acc[r][j] = 0.f;
            for (int j = 0; j < 64; j += 4) {
                float4 x0 = *(const float4*)&Fs[ty*68 + j];
                float4 x1 = *(const float4*)&Fs[(ty+32)*68 + j];
                #pragma unroll
                for (int kk2 = 0; kk2 < 4; kk2++) {
                    float4 w0 = *(const float4*)&Ws[(j+kk2)*132 + tx*8];
                    float4 w1 = *(const float4*)&Ws[(j+kk2)*132 + tx*8 + 4];
                    float wv[8] = {w0.x,w0.y,w0.z,w0.w,w1.x,w1.y,w1.z,w1.w};
                    float e0 = (kk2==0)?x0.x:(kk2==1)?x0.y:(kk2==2)?x0.z:x0.w;
                    float e1 = (kk2==0)?x1.x:(kk2==1)?x1.y:(kk2==2)?x1.z:x1.w;
                    #pragma unroll
                    for (int jx = 0; jx < 8; jx++) {
                        acc[0][jx] += e0 * wv[jx];
                        acc[1][jx] += e1 * wv[jx];
                    }
                }
            }
            #pragma unroll
            for (int rs = 0; rs < 2; rs++) {
                int r = ty + 32*rs;
                float di = dinvs[r];
                float ca = ss[r] * di;
                float cg = sqrtf(di);
                float* arow = ab + (size_t)(t0 + r) * HH + tx*8;
                *(float4*)&arow[0] = make_float4(ca*acc[rs][0],ca*acc[rs][1],ca*acc[rs][2],ca*acc[rs][3]);
                *(float4*)&arow[4] = make_float4(ca*acc[rs][4],ca*acc[rs][5],ca*acc[rs][6],ca*acc[rs][7]);
                *(float4*)&Us[r*132 + tx*8]     = make_float4(cg*acc[rs][0],cg*acc[rs][1],cg*acc[rs][2],cg*acc[rs][3]);
                *(float4*)&Us[r*132 + tx*8 + 4] = make_float4(cg*acc[rs][4],cg*acc[rs][5],cg*acc[rs][6],cg*acc[rs][7]);
            }
        }
        __syncthreads();   // B5

        // ---- P6: A0 -= Ghat^T Ghat  (skip last chunk)
        if (ch != NCH - 1) {
            const int r0 = (tid >> 4) * 4, c0 = (tid & 15) * 8;
            float acc[4][8];
            #pragma unroll
            for (int a = 0; a < 4; a++)
                #pragma unroll
                for (int h = 0; h < 8; h++) acc[a][h] = 0.f;
            for (int i = 0; i < 64; i++) {
                float4 gr  = *(const float4*)&Us[i*132 + r0];
                float4 gc0 = *(const float4*)&Us[i*132 + c0];
                float4 gc1 = *(const float4*)&Us[i*132 + c0 + 4];
                float rr[4] = {gr.x,gr.y,gr.z,gr.w};
                float cc[8] = {gc0.x,gc0.y,gc0.z,gc0.w,gc1.x,gc1.y,gc1.z,gc1.w};
                #pragma unroll
                for (int a = 0; a < 4; a++)
                    #pragma unroll
                    for (int h = 0; h < 8; h++) acc[a][h] += rr[a]*cc[h];
            }
            #pragma unroll
            for (int a = 0; a < 4; a++) {
                float4 v0 = *(float4*)&A0[(r0+a)*132 + c0];
                float4 v1 = *(float4*)&A0[(r0+a)*132 + c0 + 4];
                v0.x -= acc[a][0]; v0.y -= acc[a][1]; v0.z -= acc[a][2]; v0.w -= acc[a][3];
                v1.x -= acc[a][4]; v1.y -= acc[a][5]; v1.z -= acc[a][6]; v1.w -= acc[a][7];
                *(float4*)&A0[(r0+a)*132 + c0]     = v0;
                *(float4*)&A0[(r0+a)*132 + c0 + 4] = v1;
            }
        }
        __syncthreads();   // B6
    }
}

// ---------------------------------------------------------------------------
// Chunk sums: St_c[x][h] = sum_{t in chunk} alpha[t,x] * v[t,h]
// ---------------------------------------------------------------------------
__global__ __launch_bounds__(256) void chunk_sum_kernel(
    const float* __restrict__ alpha, const float* __restrict__ V,
    float* __restrict__ S)
{
    const int bidx = blockIdx.x;
    const int b = bidx >> 4, c = bidx & 15;
    const int tid = threadIdx.x;
    const int x0 = (tid >> 4) * 8, h0 = (tid & 15) * 8;
    const float* arow = alpha + ((size_t)b * TT + c * CP) * HH;
    const float* vrow = V + ((size_t)b * TT + c * CP) * HH;
    float acc[8][8];
    #pragma unroll
    for (int a = 0; a < 8; a++)
        #pragma unroll
        for (int h = 0; h < 8; h++) acc[a][h] = 0.f;
    for (int t = 0; t < CP; t++) {
        float4 a0 = *(const float4*)&arow[(size_t)t*HH + x0];
        float4 a1 = *(const float4*)&arow[(size_t)t*HH + x0 + 4];
        float4 v0 = *(const float4*)&vrow[(size_t)t*HH + h0];
        float4 v1 = *(const float4*)&vrow[(size_t)t*HH + h0 + 4];
        float aa[8] = {a0.x,a0.y,a0.z,a0.w,a1.x,a1.y,a1.z,a1.w};
        float vv[8] = {v0.x,v0.y,v0.z,v0.w,v1.x,v1.y,v1.z,v1.w};
        #pragma unroll
        for (int a = 0; a < 8; a++)
            #pragma unroll
            for (int h = 0; h < 8; h++) acc[a][h] += aa[a]*vv[h];
    }
    float* Sblk = S + (size_t)(b * NCP + c) * HH * HH;
    #pragma unroll
    for (int a = 0; a < 8; a++) {
        #pragma unroll
        for (int h4 = 0; h4 < 8; h4 += 4)
            *(float4*)&Sblk[(size_t)(x0+a)*HH + h0 + h4] =
                make_float4(acc[a][h4],acc[a][h4+1],acc[a][h4+2],acc[a][h4+3]);
    }
}

// ---------------------------------------------------------------------------
// Chunk output: O_c = tril(Qc alpha_c^T) Vc + Qc M_c^T
// ---------------------------------------------------------------------------
__global__ __launch_bounds__(256) void chunk_out_kernel(
    const float* __restrict__ Qm, const float* __restrict__ alpha,
    const float* __restrict__ V, const float* __restrict__ S,
    float* __restrict__ O)
{
    extern __shared__ float lds[];
    float* Mt = lds;            // 128*132
    float* Pt = Mt + 128*132;   // 128*132

    const int bidx = blockIdx.x;
    const int b = bidx >> 4, c = bidx & 15;
    const int tid = threadIdx.x;
    const float* qrow = Qm + ((size_t)b * TT + c * CP) * HH;
    const float* arow = alpha + ((size_t)b * TT + c * CP) * HH;
    const float* vrow = V + ((size_t)b * TT + c * CP) * HH;

    for (int idx4 = tid; idx4 < (HH*HH)/4; idx4 += 256) {
        int x = idx4 >> 5;
        int h4 = (idx4 & 31) * 4;
        float4 s = make_float4(0.f,0.f,0.f,0.f);
        for (int cp = 0; cp < c; cp++) {
            float4 v = *(const float4*)&S[(size_t)(b*NCP+cp)*HH*HH + (size_t)x*HH + h4];
            s.x += v.x; s.y += v.y; s.z += v.z; s.w += v.w;
        }
        *(float4*)&Mt[x*132 + h4] = s;
    }

    {
        const int s0 = (tid >> 4) * 8, t0l = (tid & 15) * 8;
        float accB[8][8];
        #pragma unroll
        for (int a = 0; a < 8; a++)
            #pragma unroll
            for (int t = 0; t < 8; t++) accB[a][t] = 0.f;
        for (int k0 = 0; k0 < HH; k0 += 4) {
            float4 qv[8], av[8];
            #pragma unroll
            for (int t = 0; t < 8; t++) qv[t] = *(const float4*)&qrow[(size_t)(t0l+t)*HH + k0];
            #pragma unroll
            for (int a = 0; a < 8; a++) av[a] = *(const float4*)&arow[(size_t)(s0+a)*HH + k0];
            #pragma unroll
            for (int a = 0; a < 8; a++)
                #pragma unroll
                for (int t = 0; t < 8; t++)
                    accB[a][t] += av[a].x*qv[t].x + av[a].y*qv[t].y
                                + av[a].z*qv[t].z + av[a].w*qv[t].w;
        }
        __syncthreads();
        #pragma unroll
        for (int a = 0; a < 8; a++)
            #pragma unroll
            for (int t = 0; t < 8; t++) {
                int sg = s0 + a, tg = t0l + t;
                Pt[sg*132 + tg] = (sg <= tg) ? accB[a][t] : 0.f;
            }
    }
    __syncthreads();

    {
        const int tr0 = (tid >> 4) * 8, h0 = (tid & 15) * 8;
        float acc[8][8];
        #pragma unroll
        for (int a = 0; a < 8; a++)
            #pragma unroll
            for (int h = 0; h < 8; h++) acc[a][h] = 0.f;
        for (int s = 0; s < CP; s++) {
            float4 p0 = *(const float4*)&Pt[s*132 + tr0];
            float4 p1 = *(const float4*)&Pt[s*132 + tr0 + 4];
            float4 v0 = *(const float4*)&vrow[(size_t)s*HH + h0];
            float4 v1 = *(const float4*)&vrow[(size_t)s*HH + h0 + 4];
            float pp[8] = {p0.x,p0.y,p0.z,p0.w,p1.x,p1.y,p1.z,p1.w};
            float vv[8] = {v0.x,v0.y,v0.z,v0.w,v1.x,v1.y,v1.z,v1.w};
            #pragma unroll
            for (int a = 0; a < 8; a++)
                #pragma unroll
                for (int h = 0; h < 8; h++) acc[a][h] += pp[a]*vv[h];
        }
        for (int x0 = 0; x0 < HH; x0 += 4) {
            float4 qv[8];
            #pragma unroll
            for (int a = 0; a < 8; a++) qv[a] = *(const float4*)&qrow[(size_t)(tr0+a)*HH + x0];
            #pragma unroll
            for (int kk = 0; kk < 4; kk++) {
                float4 m0 = *(const float4*)&Mt[(x0+kk)*132 + h0];
                float4 m1 = *(const float4*)&Mt[(x0+kk)*132 + h0 + 4];
                float mm[8] = {m0.x,m0.y,m0.z,m0.w,m1.x,m1.y,m1.z,m1.w};
                #pragma unroll
                for (int a = 0; a < 8; a++) {
                    float qq = (kk==0)?qv[a].x:(kk==1)?qv[a].y:(kk==2)?qv[a].z:qv[a].w;
                    #pragma unroll
                    for (int h = 0; h < 8; h++) acc[a][h] += qq*mm[h];
                }
            }
        }
        float* orow = O + ((size_t)b * TT + c * CP) * HH;
        #pragma unroll
        for (int a = 0; a < 8; a++) {
            #pragma unroll
            for (int h4 = 0; h4 < 8; h4 += 4)
                *(float4*)&orow[(size_t)(tr0+a)*HH + h0 + h4] =
                    make_float4(acc[a][h4],acc[a][h4+1],acc[a][h4+2],acc[a][h4+3]);
        }
    }
}

// ---------------------------------------------------------------------------
// Output: out[bt][d] = sum_h O[bt][h] * Wo[d][h] + bo[d]
// ---------------------------------------------------------------------------
__global__ __launch_bounds__(256) void out_kernel(
    const float* __restrict__ O, const float* __restrict__ Wo,
    const float* __restrict__ bo, float* __restrict__ out)
{
    const int row0 = blockIdx.x * 64;
    const int d0   = blockIdx.y * 128;

    __shared__ float oT[32][68];
    __shared__ float woT[32][132];

    const int tid = threadIdx.x;
    const int tx = tid & 15;
    const int ty = tid >> 4;

    float acc[4][8];
    #pragma unroll
    for (int i = 0; i < 4; i++)
        #pragma unroll
        for (int j = 0; j < 8; j++) acc[i][j] = 0.f;

    for (int k0 = 0; k0 < HH; k0 += 32) {
        #pragma unroll
        for (int l = 0; l < 2; l++) {
            int f = tid + l * 256;
            int r = f >> 3;
            int cg = f & 7;
            float4 v = *(const float4*)(O + (size_t)(row0 + r) * HH + k0 + cg * 4);
            oT[cg*4+0][r] = v.x; oT[cg*4+1][r] = v.y;
            oT[cg*4+2][r] = v.z; oT[cg*4+3][r] = v.w;
        }
        #pragma unroll
        for (int l = 0; l < 4; l++) {
            int f = tid + l * 256;
            int d = f >> 3;
            int cg = f & 7;
            float4 v = *(const float4*)(Wo + (size_t)(d0 + d) * HH + k0 + cg * 4);
            woT[cg*4+0][d] = v.x; woT[cg*4+1][d] = v.y;
            woT[cg*4+2][d] = v.z; woT[cg*4+3][d] = v.w;
        }
        __syncthreads();
        #pragma unroll
        for (int kk = 0; kk < 32; kk++) {
            float4 ov = *(const float4*)&oT[kk][ty * 4];
            float4 w0 = *(const float4*)&woT[kk][tx * 8];
            float4 w1 = *(const float4*)&woT[kk][tx * 8 + 4];
            float oa[4] = {ov.x, ov.y, ov.z, ov.w};
            float wa[8] = {w0.x, w0.y, w0.z, w0.w, w1.x, w1.y, w1.z, w1.w};
            #pragma unroll
            for (int i = 0; i < 4; i++)
                #pragma unroll
                for (int j = 0; j < 8; j++)
                    acc[i][j] += oa[i] * wa[j];
        }
        __syncthreads();
    }

    #pragma unroll
    for (int i = 0; i < 4; i++) {
        int row = row0 + ty * 4 + i;
        #pragma unroll
        for (int j = 0; j < 8; j++) acc[i][j] += bo[d0 + tx * 8 + j];
        float4 o0 = {acc[i][0], acc[i][1], acc[i][2], acc[i][3]};
        float4 o1 = {acc[i][4], acc[i][5], acc[i][6], acc[i][7]};
        *(float4*)(out + (size_t)row * DD + d0 + tx * 8)     = o0;
        *(float4*)(out + (size_t)row * DD + d0 + tx * 8 + 4) = o1;
    }
}

extern "C" void kernel_launch(void* const* d_in, const int* in_sizes, int n_in,
                              void* d_out, int out_size, void* d_ws, size_t ws_size,
                              hipStream_t stream) {
    const float* x  = (const float*)d_in[0];
    const float* Wq = (const float*)d_in[1];
    const float* bq = (const float*)d_in[2];
    const float* Wk = (const float*)d_in[3];
    const float* bk = (const float*)d_in[4];
    const float* Wv = (const float*)d_in[5];
    const float* bv = (const float*)d_in[6];
    const float* Wo = (const float*)d_in[7];
    const float* bo = (const float*)d_in[8];
    float* out = (float*)d_out;

    float* ws = (float*)d_ws;
    float* Q = ws;                          // BT*HH
    float* K = ws + (size_t)BT * HH;        // BT*HH (reused as O)
    float* V = ws + (size_t)2 * BT * HH;    // BT*HH
    float* S = ws + (size_t)3 * BT * HH;    // BB*NCP*HH*HH
    float* O = K;
    float* alpha = out;                     // staged in d_out

    dim3 pgrid(BT / 64, 3);
    proj_kernel<<<pgrid, 256, 0, stream>>>(x, Wq, bq, Wk, bk, Wv, bv, Q, K, V);

    const size_t p1_lds = (size_t)(128*132 + 64*132 + 64*132 + 64*68 + 64 + 64) * 4;
    pass1_kernel<<<BB, 512, p1_lds, stream>>>(Q, K, alpha);

    chunk_sum_kernel<<<BB * NCP, 256, 0, stream>>>(alpha, V, S);

    const size_t k4_lds = (size_t)(2 * 128 * 132) * 4;
    chunk_out_kernel<<<BB * NCP, 256, k4_lds, stream>>>(Q, alpha, V, S, O);

    dim3 ogrid(BT / 64, DD / 128);
    out_kernel<<<ogrid, 256, 0, stream>>>(O, Wo, bo, out);
}